// Round 9
// baseline (435.296 us; speedup 1.0000x reference)
//
#include <hip/hip_runtime.h>

#define N_NODES 100000
#define N_EDGES 1600000
#define DIM     128
#define NGRAPH  64
#define NCLS    10
#define ZROW    N_NODES   // zeroed pad row id in hbuf

#define NBLK    64                  // histogram/fill blocks
#define EPB     (N_EDGES / NBLK)    // 25000 edges per block (exact)
#define RANGE   50000               // node ids per histogram pass (2 passes)

typedef __bf16 bf16x8 __attribute__((ext_vector_type(8)));
typedef float  f32x4  __attribute__((ext_vector_type(4)));

// ---- bf16 pack/unpack helpers (manual RNE) ----------------------------------
__device__ __forceinline__ ushort f2bf(float x) {
  uint b = __float_as_uint(x);
  b += 0x7fffu + ((b >> 16) & 1u);
  return (ushort)(b >> 16);
}
__device__ __forceinline__ uint pack2(float lo, float hi) {
  return (uint)f2bf(lo) | ((uint)f2bf(hi) << 16);
}
__device__ __forceinline__ float unlo(uint u) { return __uint_as_float(u << 16); }
__device__ __forceinline__ float unhi(uint u) { return __uint_as_float(u & 0xffff0000u); }

__device__ __forceinline__ void acc8(float* a, uint4 u) {
  a[0] += unlo(u.x); a[1] += unhi(u.x);
  a[2] += unlo(u.y); a[3] += unhi(u.y);
  a[4] += unlo(u.z); a[5] += unhi(u.z);
  a[6] += unlo(u.w); a[7] += unhi(u.w);
}

// ---------------- init: zero pool, cnt, pad row ------------------------------
__global__ void k_init(float* __restrict__ pool, float* __restrict__ cnt,
                       uint* __restrict__ padrow) {
  int t = threadIdx.x;
  for (int i = t; i < NGRAPH * DIM; i += 256) pool[i] = 0.f;
  if (t < NGRAPH) cnt[t] = 0.f;
  if (t < DIM / 2) padrow[t] = 0u;
}

// ---------------- LDS-privatized degree histograms ---------------------------
__global__ __launch_bounds__(256)
void k_hist(const int* __restrict__ src, const int* __restrict__ dst,
            ushort* __restrict__ part) {
  extern __shared__ uint cnt[];   // RANGE/2 words = 100 KB
  int p = blockIdx.y;
  int b = blockIdx.x;
  const int* ids = (p < 2) ? dst : src;
  int base = (p & 1) * RANGE;
  for (int i = threadIdx.x; i < RANGE / 2; i += 256) cnt[i] = 0;
  __syncthreads();
  int cb = b * EPB;
  for (int j = threadIdx.x; j < EPB; j += 256) {
    int v = ids[cb + j] - base;
    if ((unsigned)v < RANGE) atomicAdd(&cnt[v >> 1], 1u << ((v & 1) * 16));
  }
  __syncthreads();
  uint* out = (uint*)(part + ((size_t)p * NBLK + b) * RANGE);
  for (int i = threadIdx.x; i < RANGE / 2; i += 256) out[i] = cnt[i];
}

// ---------------- sum partials -> degrees + per-block exclusive prefix -------
__global__ void k_degsum(const ushort* __restrict__ part, int* __restrict__ deg_in,
                         int* __restrict__ deg_out, ushort* __restrict__ pre) {
  int n = blockIdx.x * 256 + threadIdx.x;
  if (n >= N_NODES) return;
  int r = n / RANGE, i = n % RANGE;
  const ushort* pin  = part + ((size_t)r * NBLK) * RANGE + i;        // dst pass
  const ushort* pout = part + ((size_t)(2 + r) * NBLK) * RANGE + i;  // src pass
  int sin = 0, sout = 0;
  for (int b = 0; b < NBLK; ++b) {
    pre[(size_t)b * N_NODES + n] = (ushort)sin;
    sin  += pin[(size_t)b * RANGE];
    sout += pout[(size_t)b * RANGE];
  }
  deg_in[n] = sin;
  deg_out[n] = sout;
}

// ---------------- prefix scan of deg_in -> row_ptr ---------------------------
__global__ void k_blocksum(const int* __restrict__ deg_in, int* __restrict__ bsum) {
  __shared__ int s[256];
  int i = blockIdx.x * 256 + threadIdx.x;
  s[threadIdx.x] = (i < N_NODES) ? deg_in[i] : 0;
  __syncthreads();
  for (int off = 128; off > 0; off >>= 1) {
    if (threadIdx.x < off) s[threadIdx.x] += s[threadIdx.x + off];
    __syncthreads();
  }
  if (threadIdx.x == 0) bsum[blockIdx.x] = s[0];
}

__global__ void k_scan_bsum(int* __restrict__ bsum, int nb) {
  __shared__ int s[512];
  int t = threadIdx.x;
  int v = (t < nb) ? bsum[t] : 0;
  s[t] = v;
  __syncthreads();
  for (int off = 1; off < 512; off <<= 1) {
    int x = (t >= off) ? s[t - off] : 0;
    __syncthreads();
    s[t] += x;
    __syncthreads();
  }
  if (t < nb) bsum[t] = s[t] - v;  // exclusive
}

__global__ void k_rowptr(const int* __restrict__ deg_in, const int* __restrict__ bsum,
                         int* __restrict__ row_ptr) {
  __shared__ int s[256];
  int t = threadIdx.x;
  int i = blockIdx.x * 256 + t;
  int v = (i < N_NODES) ? deg_in[i] : 0;
  s[t] = v;
  __syncthreads();
  for (int off = 1; off < 256; off <<= 1) {
    int x = (t >= off) ? s[t - off] : 0;
    __syncthreads();
    s[t] += x;
    __syncthreads();
  }
  if (i < N_NODES) row_ptr[i] = bsum[blockIdx.x] + s[t] - v;
  if (i == N_NODES - 1) row_ptr[N_NODES] = bsum[blockIdx.x] + s[t];
}

// ---------------- ranked CSR fill (no global atomics) ------------------------
__global__ __launch_bounds__(256)
void k_fillrank(const int* __restrict__ src, const int* __restrict__ dst,
                const int* __restrict__ row_ptr, const ushort* __restrict__ pre,
                int* __restrict__ csr_src) {
  extern __shared__ uint rk[];    // RANGE/2 words
  int b = blockIdx.x;
  int base = blockIdx.y * RANGE;
  for (int i = threadIdx.x; i < RANGE / 2; i += 256) rk[i] = 0;
  __syncthreads();
  int cb = b * EPB;
  for (int j = threadIdx.x; j < EPB; j += 256) {
    int d = dst[cb + j];
    int s = src[cb + j];
    int v = d - base;
    if ((unsigned)v < RANGE) {
      uint old = atomicAdd(&rk[v >> 1], 1u << ((v & 1) * 16));
      int rank = (old >> ((v & 1) * 16)) & 0xffff;
      int pos = row_ptr[d] + pre[(size_t)b * N_NODES + d] + rank;
      csr_src[pos] = s;
    }
  }
}

// ---------------- W -> bf16 transposed (B^T layout: Wt[c][k]) ----------------
__global__ void k_convW(const float* __restrict__ W1, const float* __restrict__ W2,
                        ushort* __restrict__ Wt1, ushort* __restrict__ Wt2) {
  int idx = blockIdx.x * 256 + threadIdx.x;
  const float* W = (idx < 16384) ? W1 : W2;
  ushort* Wt = (idx < 16384) ? Wt1 : Wt2;
  int t = idx & 16383;
  int c = t >> 7, k = t & 127;
  Wt[c * 128 + k] = f2bf(W[k * 128 + c]);
}

// ---------------- prescale: hs = bf16(h * rsqrt(deg_out[row])) ---------------
__global__ void k_prescale(const float4* __restrict__ h4, const int* __restrict__ deg_out,
                           uint4* __restrict__ out4) {
  int idx = blockIdx.x * blockDim.x + threadIdx.x;
  if (idx < N_NODES * 16) {
    int row = idx >> 4;
    int d = deg_out[row];
    float s = d > 0 ? rsqrtf((float)d) : 0.f;
    float4 v0 = h4[idx * 2];
    float4 v1 = h4[idx * 2 + 1];
    uint4 o;
    o.x = pack2(v0.x * s, v0.y * s);
    o.y = pack2(v0.z * s, v0.w * s);
    o.z = pack2(v1.x * s, v1.y * s);
    o.w = pack2(v1.z * s, v1.w * s);
    out4[idx] = o;
  }
}

// ---------------- fused gather + MFMA GEMM (group-per-node) ------------------
// Block = 4 waves = one 16-row strip. Wave = 4x16-lane groups, ONE node per
// group: lane li of group g owns columns li*8..li*8+7 of node g and
// accumulates over ALL its edges -> no cross-lane reduce. 4-deep edge unroll
// gives 16 independent 16B loads in flight per wave. Tail edges hit the
// L1-resident zero pad row (branchless). B-frags load after gather.
__global__ __launch_bounds__(256)
void k_gg(const uint* __restrict__ hs, const int* __restrict__ row_ptr,
          const int* __restrict__ csr_src, const ushort* __restrict__ Wt,
          const float* __restrict__ bias, const int* __restrict__ deg_scale,
          ushort* __restrict__ out) {
  __shared__ ushort As[16][136];   // row stride 272B = 17 x 16B: conflict-benign
  int wv = threadIdx.x >> 6, lane = threadIdx.x & 63;
  int strip = blockIdx.x;
  int g = lane >> 4;      // group = node slot within wave
  int li = lane & 15;     // 16B column segment slot
  int glane = g * 16;

  int n = strip * 16 + wv * 4 + g;
  int beg = row_ptr[n];
  int deg = row_ptr[n + 1] - beg;

  float a[8] = {};

  // prefetch chunk 0's indices (one per lane; li beyond deg -> zero row)
  int nxt = (li < deg) ? csr_src[beg + li] : ZROW;
  for (int cb = 0; cb < deg; cb += 16) {
    int idx = nxt;
    int rem = deg - cb - 16;
    if (rem > 0) nxt = (li < rem) ? csr_src[beg + cb + 16 + li] : ZROW;
    #pragma unroll
    for (int e = 0; e < 16; e += 4) {
      int s0 = __shfl(idx, glane + e);
      int s1 = __shfl(idx, glane + e + 1);
      int s2 = __shfl(idx, glane + e + 2);
      int s3 = __shfl(idx, glane + e + 3);
      uint4 u0 = *(const uint4*)(hs + (size_t)s0 * 64 + li * 4);
      uint4 u1 = *(const uint4*)(hs + (size_t)s1 * 64 + li * 4);
      uint4 u2 = *(const uint4*)(hs + (size_t)s2 * 64 + li * 4);
      uint4 u3 = *(const uint4*)(hs + (size_t)s3 * 64 + li * 4);
      acc8(a, u0); acc8(a, u1); acc8(a, u2); acc8(a, u3);
    }
  }

  // dst-side norm + bf16 pack; every lane stores its 16B segment
  {
    float sc = deg > 0 ? rsqrtf((float)deg) : 0.f;
    uint4 o;
    o.x = pack2(a[0] * sc, a[1] * sc);
    o.y = pack2(a[2] * sc, a[3] * sc);
    o.z = pack2(a[4] * sc, a[5] * sc);
    o.w = pack2(a[6] * sc, a[7] * sc);
    *(uint4*)&As[wv * 4 + g][li * 8] = o;
  }

  // B fragments: wave's 2 col-tiles (loaded post-gather; L2-hot weights)
  int lr = lane & 15, lk = lane >> 4;
  bf16x8 bfrag[4][2];
  #pragma unroll
  for (int ks = 0; ks < 4; ++ks)
    #pragma unroll
    for (int c2 = 0; c2 < 2; ++c2)
      bfrag[ks][c2] = *(const bf16x8*)(Wt + (size_t)((wv * 2 + c2) * 16 + lr) * 128 +
                                       ks * 32 + lk * 8);
  __syncthreads();

  f32x4 acc[2] = {};
  #pragma unroll
  for (int ks = 0; ks < 4; ++ks) {
    bf16x8 af = *(const bf16x8*)&As[lr][ks * 32 + lk * 8];
    acc[0] = __builtin_amdgcn_mfma_f32_16x16x32_bf16(af, bfrag[ks][0], acc[0], 0, 0, 0);
    acc[1] = __builtin_amdgcn_mfma_f32_16x16x32_bf16(af, bfrag[ks][1], acc[1], 0, 0, 0);
  }

  #pragma unroll
  for (int rr = 0; rr < 4; ++rr) {
    int row = strip * 16 + lk * 4 + rr;
    float s = 1.f;
    if (deg_scale) {
      int d = deg_scale[row];
      s = d > 0 ? rsqrtf((float)d) : 0.f;
    }
    #pragma unroll
    for (int c2 = 0; c2 < 2; ++c2) {
      int col = (wv * 2 + c2) * 16 + lr;
      float v = fmaxf(acc[c2][rr] + bias[col], 0.f) * s;
      out[(size_t)row * 128 + col] = f2bf(v);
    }
  }
}

// ---------------- segmented mean-pool: 64 rows per wave ----------------------
__global__ __launch_bounds__(256)
void k_pool(const uint* __restrict__ h, const int* __restrict__ gid,
            float* __restrict__ pool, float* __restrict__ cnt) {
  int wave = threadIdx.x >> 6, lane = threadIdx.x & 63;
  int start = blockIdx.x * 256 + wave * 64;
  if (start >= N_NODES) return;
  int end = min(start + 64, N_NODES);
  float ax = 0.f, ay = 0.f;
  int g = gid[start];
  int seglen = 0;
  for (int i = start; i < end; ++i) {
    int gi = gid[i];
    if (gi != g) {
      atomicAdd(&pool[g * DIM + 2 * lane], ax);
      atomicAdd(&pool[g * DIM + 2 * lane + 1], ay);
      if (lane == 0) atomicAdd(&cnt[g], (float)seglen);
      ax = ay = 0.f;
      seglen = 0;
      g = gi;
    }
    uint u = h[(size_t)i * 64 + lane];
    ax += unlo(u);
    ay += unhi(u);
    ++seglen;
  }
  atomicAdd(&pool[g * DIM + 2 * lane], ax);
  atomicAdd(&pool[g * DIM + 2 * lane + 1], ay);
  if (lane == 0) atomicAdd(&cnt[g], (float)seglen);
}

// ---------------- classifier -------------------------------------------------
__global__ void k_classifier(const float* __restrict__ pool, const float* __restrict__ cnt,
                             const float* __restrict__ Wc, const float* __restrict__ bc,
                             float* __restrict__ out) {
  int t = threadIdx.x;
  if (t >= NGRAPH * NCLS) return;
  int g = t / NCLS, c = t % NCLS;
  float inv = 1.f / fmaxf(cnt[g], 1.f);
  float s = bc[c];
  for (int k = 0; k < DIM; ++k) s += pool[g * DIM + k] * inv * Wc[k * NCLS + c];
  out[g * NCLS + c] = s;
}

// -----------------------------------------------------------------------------
extern "C" void kernel_launch(void* const* d_in, const int* in_sizes, int n_in,
                              void* d_out, int out_size, void* d_ws, size_t ws_size,
                              hipStream_t stream) {
  const float* h   = (const float*)d_in[0];
  const int* src   = (const int*)d_in[1];
  const int* dst   = (const int*)d_in[2];
  const int* gid   = (const int*)d_in[3];
  const float* W1  = (const float*)d_in[4];
  const float* b1  = (const float*)d_in[5];
  const float* W2  = (const float*)d_in[6];
  const float* b2  = (const float*)d_in[7];
  const float* Wc  = (const float*)d_in[8];
  const float* bc  = (const float*)d_in[9];
  float* out = (float*)d_out;

  size_t off = 0;
  auto alloc = [&](size_t bytes) -> char* {
    char* p = (char*)d_ws + off;
    off += (bytes + 255) & ~(size_t)255;
    return p;
  };
  ushort* h2buf   = (ushort*)alloc((size_t)N_NODES * DIM * 2);        // 25.6 MB
  int*    csr_src = (int*)alloc((size_t)N_EDGES * 4);                 //  6.4 MB
  int*    row_ptr = (int*)alloc((size_t)(N_NODES + 1) * 4);
  int*    bsum    = (int*)alloc(512 * 4);
  ushort* Wt1     = (ushort*)alloc(16384 * 2);
  ushort* Wt2     = (ushort*)alloc(16384 * 2);
  ushort* hbuf    = (ushort*)alloc((size_t)(N_NODES + 1) * DIM * 2);  // 25.6 MB (+pad row)
  uint*   padrow  = (uint*)(hbuf + (size_t)N_NODES * DIM);
  // partials region; dead after k_degsum -> reused as layer-1 output (h1buf)
  ushort* part    = (ushort*)alloc((size_t)4 * NBLK * RANGE * 2);     // 25.6 MB
  ushort* h1buf   = part;                                             // alias (same size)
  ushort* pre     = (ushort*)alloc((size_t)NBLK * N_NODES * 2);       // 12.8 MB
  int*    deg_out = (int*)alloc((size_t)N_NODES * 4);
  int*    deg_in  = (int*)alloc((size_t)N_NODES * 4);
  float*  pool    = (float*)alloc((size_t)NGRAPH * DIM * 4);
  float*  cnt     = (float*)alloc((size_t)NGRAPH * 4);
  (void)ws_size; (void)in_sizes; (void)n_in; (void)out_size;

  const int NB = (N_NODES + 255) / 256;   // 391
  const size_t HIST_LDS = (RANGE / 2) * sizeof(uint);  // 100 KB dynamic LDS

  k_init<<<1, 256, 0, stream>>>(pool, cnt, padrow);
  k_hist<<<dim3(NBLK, 4), 256, HIST_LDS, stream>>>(src, dst, part);
  k_degsum<<<NB, 256, 0, stream>>>(part, deg_in, deg_out, pre);
  k_blocksum<<<NB, 256, 0, stream>>>(deg_in, bsum);
  k_scan_bsum<<<1, 512, 0, stream>>>(bsum, NB);
  k_rowptr<<<NB, 256, 0, stream>>>(deg_in, bsum, row_ptr);
  k_fillrank<<<dim3(NBLK, 2), 256, HIST_LDS, stream>>>(src, dst, row_ptr, pre, csr_src);
  k_convW<<<128, 256, 0, stream>>>(W1, W2, Wt1, Wt2);
  k_prescale<<<(N_NODES * 16 + 255) / 256, 256, 0, stream>>>((const float4*)h, deg_out,
                                                             (uint4*)hbuf);
  // layer 1: fused gather + GEMM (+bias+relu+next-layer src norm)
  k_gg<<<N_NODES / 16, 256, 0, stream>>>((const uint*)hbuf, row_ptr, csr_src,
                                         Wt1, b1, deg_out, h1buf);
  // layer 2: fused gather + GEMM (+bias+relu)
  k_gg<<<N_NODES / 16, 256, 0, stream>>>((const uint*)h1buf, row_ptr, csr_src,
                                         Wt2, b2, nullptr, h2buf);
  // pool + classify
  k_pool<<<(N_NODES + 255) / 256, 256, 0, stream>>>((const uint*)h2buf, gid, pool, cnt);
  k_classifier<<<1, 640, 0, stream>>>(pool, cnt, Wc, bc, out);
}